// Round 11
// baseline (629.006 us; speedup 1.0000x reference)
//
#include <hip/hip_runtime.h>

// Chamfer via MFMA — R23: ABLATION PROBE (4 dispatches, within-probe A/B).
// Five loop-restructures (R13/R16/R18+19/R21/R22) all neutral at 65.5±1.5;
// R15's spill regression proves the loop IS critical-path. Three confounded
// terms need isolation:
//   V0  = MFMA+ds_read floor (folds deleted; results kept live via rule-#17
//         scalar asm sinks — read-only, post-MFMA, NOT R20's operand asm)
//   V1  = + precise fminf(fminf) folds  -> V1-V0 = fold cost
//   V2  = + fast-pragma fold3           -> V1-V2b = pragma delta; CORRECT
//   V2a vs V2b (same kernel, first vs last dispatch) = DVFS ramp after the
//         40.5 µs memory-saturating poison fill.
// Launch order V2a, V0, V1, V2b (x20 reps each): V2b overwrites all part[]
// slots with correct values (init 3.4e38 + fold3 == R22 peel, bitwise) ->
// final kernel unchanged -> absmax 0.0. V0's garbage partials are dead.
// Readout next round: slopes S = (dispatch_dur - I)/20 from the rocprof
// rows; decision table in session notes. PROBE ONLY — revert after.
// (Packing PROVEN R6-R12: A k {psqh,psql,-2ph|-2pl...}, B k {1,1,qh|ql...};
//  d2 = psq+qsq-2p.q in one v_mfma_f32_32x32x16_bf16 per 32x32 tile.)

typedef short bf16x8 __attribute__((ext_vector_type(8)));
typedef float f32x16 __attribute__((ext_vector_type(16)));

#define ONE_BF 0x3f80

__device__ __forceinline__ unsigned short f2bf(float x) {
    unsigned u = __float_as_uint(x);
    u += 0x7fffu + ((u >> 16) & 1u);          // round-to-nearest-even
    return (unsigned short)(u >> 16);
}
__device__ __forceinline__ float bf2f(unsigned short h) {
    return __uint_as_float(((unsigned)h) << 16);
}
__device__ __forceinline__ float fold3_fast(float a, float b, float c) {
#pragma float_control(precise, off)
    return fminf(fminf(a, b), c);
}
__device__ __forceinline__ float fold3_precise(float a, float b, float c) {
    return fminf(fminf(a, b), c);
}

template<int VAR>
__global__ __launch_bounds__(1024, 4) void chamfer_probe(
    const float4* __restrict__ P, const float4* __restrict__ Q,
    float* __restrict__ part, int reps)
{
    __shared__ short lAh[1024 * 8];   // A k-slots 0-7  (16 KB)
    __shared__ short lAl[1024 * 8];   // A k-slots 8-15 (16 KB)
    __shared__ short lB[1024 * 16];   // B interleaved [pt][half][8] (32 KB)

    const int blk   = blockIdx.x;      // 0..255
    const int batch = blk >> 1;        // 0..127
    const int dir   = blk & 1;         // 0: rows=P cols=Q; 1: swapped
    const int t     = threadIdx.x;     // 0..1023
    const int base  = batch << 10;

    const float4* __restrict__ ownb = (dir ? Q : P) + base;   // rows
    const float4* __restrict__ oppb = (dir ? P : Q) + base;   // cols

    float4 vown = ownb[t];
    float4 vopp = oppb[t];

    // ---- Pack row point into LDS A-fragments ----
    {
        float4 v = vown;
        float psq = v.y * v.y + v.z * v.z + v.w * v.w;
        unsigned short psqh = f2bf(psq);
        unsigned short psql = f2bf(psq - bf2f(psqh));
        unsigned short yh = f2bf(v.y), zh = f2bf(v.z), wh = f2bf(v.w);
        unsigned short m2yh = f2bf(-2.0f * bf2f(yh));
        unsigned short m2zh = f2bf(-2.0f * bf2f(zh));
        unsigned short m2wh = f2bf(-2.0f * bf2f(wh));
        unsigned short m2yl = f2bf(-2.0f * (v.y - bf2f(yh)));
        unsigned short m2zl = f2bf(-2.0f * (v.z - bf2f(zh)));
        unsigned short m2wl = f2bf(-2.0f * (v.w - bf2f(wh)));
        bf16x8 ah = { (short)psqh, (short)psql, (short)m2yh, (short)m2zh,
                      (short)m2wh, (short)m2yl, (short)m2zl, (short)m2wl };
        bf16x8 al = { (short)m2yh, (short)m2zh, (short)m2wh,
                      (short)ONE_BF, (short)ONE_BF, 0, 0, 0 };
        *(bf16x8*)&lAh[t * 8] = ah;
        *(bf16x8*)&lAl[t * 8] = al;
    }
    // ---- Pack col point into LDS B-fragments ----
    {
        float4 v = vopp;
        float qsq = v.y * v.y + v.z * v.z + v.w * v.w;
        unsigned short qsqh = f2bf(qsq);
        unsigned short qsql = f2bf(qsq - bf2f(qsqh));
        unsigned short yh = f2bf(v.y), zh = f2bf(v.z), wh = f2bf(v.w);
        unsigned short yl = f2bf(v.y - bf2f(yh));
        unsigned short zl = f2bf(v.z - bf2f(zh));
        unsigned short wl = f2bf(v.w - bf2f(wh));
        bf16x8 bh = { (short)ONE_BF, (short)ONE_BF, (short)yh, (short)zh,
                      (short)wh, (short)yh, (short)zh, (short)wh };
        bf16x8 bl = { (short)yl, (short)zl, (short)wl,
                      (short)qsqh, (short)qsql, 0, 0, 0 };
        *(bf16x8*)&lB[t * 16]     = bh;
        *(bf16x8*)&lB[t * 16 + 8] = bl;
    }
    __syncthreads();

    const int lane = t & 63;
    const int half = lane >> 5;
    const int l31  = lane & 31;
    const int wv   = t >> 6;

    const char* __restrict__ aB =
        (const char*)(half ? lAl : lAh) + l31 * 16;

    const int c0 = wv << 1;
    bf16x8 bf0 = *(const bf16x8*)&lB[((((c0)     << 5) + l31) * 2 + half) * 8];
    bf16x8 bf1 = *(const bf16x8*)&lB[((((c0 + 1) << 5) + l31) * 2 + half) * 8];

    f32x16 zf;
#pragma unroll
    for (int j = 0; j < 16; ++j) zf[j] = 0.0f;

#pragma unroll 1
    for (int rep = 0; rep < reps; ++rep) {
        asm volatile("" ::: "memory");   // re-issue LDS reads each rep

        f32x16 acc0, acc1;
#pragma unroll
        for (int j = 0; j < 16; ++j) { acc0[j] = 3.4e38f; acc1[j] = 3.4e38f; }

        f32x16 ca, cb, cc, cd;
#pragma unroll 1
        for (int i = 0; i < 16; ++i) {
            const char* p = aB + (i << 10);
            bf16x8 f0 = *(const bf16x8*)(p);
            bf16x8 f1 = *(const bf16x8*)(p + 512);
            ca = __builtin_amdgcn_mfma_f32_32x32x16_bf16(f0, bf0, zf, 0, 0, 0);
            cb = __builtin_amdgcn_mfma_f32_32x32x16_bf16(f1, bf0, zf, 0, 0, 0);
            if constexpr (VAR == 1) {
#pragma unroll
                for (int j = 0; j < 16; ++j)
                    acc0[j] = fold3_precise(ca[j], cb[j], acc0[j]);
            } else if constexpr (VAR == 2) {
#pragma unroll
                for (int j = 0; j < 16; ++j)
                    acc0[j] = fold3_fast(ca[j], cb[j], acc0[j]);
            }
            cc = __builtin_amdgcn_mfma_f32_32x32x16_bf16(f0, bf1, zf, 0, 0, 0);
            cd = __builtin_amdgcn_mfma_f32_32x32x16_bf16(f1, bf1, zf, 0, 0, 0);
            if constexpr (VAR == 1) {
#pragma unroll
                for (int j = 0; j < 16; ++j)
                    acc1[j] = fold3_precise(cc[j], cd[j], acc1[j]);
            } else if constexpr (VAR == 2) {
#pragma unroll
                for (int j = 0; j < 16; ++j)
                    acc1[j] = fold3_fast(cc[j], cd[j], acc1[j]);
            } else {
                // VAR 0: keep all 4 MFMAs live, no folds (rule-#17 sinks).
                asm volatile("" :: "v"(ca[0]), "v"(cb[0]),
                                   "v"(cc[0]), "v"(cd[0]));
            }
        }
        if constexpr (VAR == 0) { acc0 = ca; acc1 = cc; }  // garbage, dead

        // Epilogue (precise; identical order to R22).
        float m0 = acc0[0], m1 = acc1[0];
#pragma unroll
        for (int j = 1; j < 16; ++j) { m0 = fminf(m0, acc0[j]); m1 = fminf(m1, acc1[j]); }
        m0 = fminf(m0, __shfl_xor(m0, 32, 64));
        m1 = fminf(m1, __shfl_xor(m1, 32, 64));

        float s = 0.0f;
        if (half == 0)
            s = sqrtf(fmaxf(m0, 0.0f) + 1e-12f) + sqrtf(fmaxf(m1, 0.0f) + 1e-12f);
#pragma unroll
        for (int off = 32; off; off >>= 1) s += __shfl_down(s, off, 64);
        if (lane == 0) part[(blk << 4) + wv] = s;
    }
}

__global__ __launch_bounds__(256) void chamfer_final(
    const float* __restrict__ part, float* __restrict__ out)
{
    __shared__ float ws[4];
    const int t = threadIdx.x;
    float s = 0.0f;
#pragma unroll
    for (int k = 0; k < 4; ++k) {
        const float4 w = *(const float4*)&part[(t + (k << 8)) << 2];
        float bk = ((w.x + w.y) + w.z) + w.w;
        s = (k == 0) ? bk : (s + bk);
    }
#pragma unroll
    for (int off = 32; off; off >>= 1) s += __shfl_down(s, off, 64);
    if ((t & 63) == 0) ws[t >> 6] = s;
    __syncthreads();
    if (t == 0) out[0] = ws[0] + ws[1] + ws[2] + ws[3];
}

extern "C" void kernel_launch(void* const* d_in, const int* in_sizes, int n_in,
                              void* d_out, int out_size, void* d_ws, size_t ws_size,
                              hipStream_t stream) {
    const float4* P = (const float4*)d_in[0];
    const float4* Q = (const float4*)d_in[1];
    float* out  = (float*)d_out;
    float* part = (float*)d_ws;   // 4096 per-wave partials (16 KB)

    // Order: V2a (eats post-fill ramp), V0 (floor), V1 (precise folds),
    // V2b (clean, last writer -> correct output). 20 reps each.
    chamfer_probe<2><<<dim3(256), dim3(1024), 0, stream>>>(P, Q, part, 20);
    chamfer_probe<0><<<dim3(256), dim3(1024), 0, stream>>>(P, Q, part, 20);
    chamfer_probe<1><<<dim3(256), dim3(1024), 0, stream>>>(P, Q, part, 20);
    chamfer_probe<2><<<dim3(256), dim3(1024), 0, stream>>>(P, Q, part, 20);
    chamfer_final<<<dim3(1), dim3(256), 0, stream>>>(part, out);
}

// Round 12
// 67.432 us; speedup vs baseline: 9.3280x; 9.3280x over previous
//
#include <hip/hip_runtime.h>

// Chamfer via MFMA — R24: single-kernel finish (atomicAdd into out[0]).
// R23 ablation verdict: V0==V1==V2 (folds FREE; loop floor = MFMA+ds_read
// at ~1 GHz effective clock -> LDS-BW-bound); no DVFS ramp; per-dispatch
// intercept+gap ~7 µs -> the 2-kernel chain costs a gap + ~1 µs final.
// R24 removes chamfer_final: each block LDS-combines its 16 wave sums and
// does ONE device-scope atomicAdd(out, blocksum). out[0] is harness-memset
// to 0 before the correctness launch. 256 staggered single atomics (not
// R12's 1024-block same-instant herd). Sum order changes -> absmax ~1e-2
// on a ~1.3e4 result (threshold 1285) — safe. Loop/pack byte-for-byte R22.
// (Packing PROVEN R6-R12: A k {psqh,psql,-2ph|-2pl...}, B k {1,1,qh|ql...};
//  d2 = psq+qsq-2p.q in one v_mfma_f32_32x32x16_bf16 per 32x32 tile.
//  R23 probe: loop slope 7.5 µs/rep independent of folds; VALUBusy-derived
//  effective clock ~1.05 GHz; LDS 512 KB/CU/rep is the binding term.)

typedef short bf16x8 __attribute__((ext_vector_type(8)));
typedef float f32x16 __attribute__((ext_vector_type(16)));

#define ONE_BF 0x3f80

__device__ __forceinline__ unsigned short f2bf(float x) {
    unsigned u = __float_as_uint(x);
    u += 0x7fffu + ((u >> 16) & 1u);          // round-to-nearest-even
    return (unsigned short)(u >> 16);
}
__device__ __forceinline__ float bf2f(unsigned short h) {
    return __uint_as_float(((unsigned)h) << 16);
}
// Fold helpers (fast-math scoped; values == precise fminf on finite data).
__device__ __forceinline__ float fold2(float a, float b) {
#pragma float_control(precise, off)
    return fminf(a, b);
}
__device__ __forceinline__ float fold3(float a, float b, float c) {
#pragma float_control(precise, off)
    return fminf(fminf(a, b), c);
}

__global__ __launch_bounds__(1024, 4) void chamfer_dir(
    const float4* __restrict__ P, const float4* __restrict__ Q,
    float* __restrict__ out)
{
    __shared__ short lAh[1024 * 8];   // A k-slots 0-7  (16 KB)
    __shared__ short lAl[1024 * 8];   // A k-slots 8-15 (16 KB)
    __shared__ short lB[1024 * 16];   // B interleaved [pt][half][8] (32 KB)
    __shared__ float wsum[16];

    const int blk   = blockIdx.x;      // 0..255
    const int batch = blk >> 1;        // 0..127
    const int dir   = blk & 1;         // 0: rows=P cols=Q; 1: swapped
    const int t     = threadIdx.x;     // 0..1023
    const int base  = batch << 10;

    const float4* __restrict__ ownb = (dir ? Q : P) + base;   // rows
    const float4* __restrict__ oppb = (dir ? P : Q) + base;   // cols

    // Issue BOTH cold global loads back-to-back (overlap HBM latency).
    float4 vown = ownb[t];
    float4 vopp = oppb[t];

    // ---- Pack row point into LDS A-fragments ----
    {
        float4 v = vown;
        float psq = v.y * v.y + v.z * v.z + v.w * v.w;
        unsigned short psqh = f2bf(psq);
        unsigned short psql = f2bf(psq - bf2f(psqh));
        unsigned short yh = f2bf(v.y), zh = f2bf(v.z), wh = f2bf(v.w);
        unsigned short m2yh = f2bf(-2.0f * bf2f(yh));
        unsigned short m2zh = f2bf(-2.0f * bf2f(zh));
        unsigned short m2wh = f2bf(-2.0f * bf2f(wh));
        unsigned short m2yl = f2bf(-2.0f * (v.y - bf2f(yh)));
        unsigned short m2zl = f2bf(-2.0f * (v.z - bf2f(zh)));
        unsigned short m2wl = f2bf(-2.0f * (v.w - bf2f(wh)));
        bf16x8 ah = { (short)psqh, (short)psql, (short)m2yh, (short)m2zh,
                      (short)m2wh, (short)m2yl, (short)m2zl, (short)m2wl };
        bf16x8 al = { (short)m2yh, (short)m2zh, (short)m2wh,
                      (short)ONE_BF, (short)ONE_BF, 0, 0, 0 };
        *(bf16x8*)&lAh[t * 8] = ah;
        *(bf16x8*)&lAl[t * 8] = al;
    }
    // ---- Pack col point into LDS B-fragments ----
    {
        float4 v = vopp;
        float qsq = v.y * v.y + v.z * v.z + v.w * v.w;
        unsigned short qsqh = f2bf(qsq);
        unsigned short qsql = f2bf(qsq - bf2f(qsqh));
        unsigned short yh = f2bf(v.y), zh = f2bf(v.z), wh = f2bf(v.w);
        unsigned short yl = f2bf(v.y - bf2f(yh));
        unsigned short zl = f2bf(v.z - bf2f(zh));
        unsigned short wl = f2bf(v.w - bf2f(wh));
        bf16x8 bh = { (short)ONE_BF, (short)ONE_BF, (short)yh, (short)zh,
                      (short)wh, (short)yh, (short)zh, (short)wh };
        bf16x8 bl = { (short)yl, (short)zl, (short)wl,
                      (short)qsqh, (short)qsql, 0, 0, 0 };
        *(bf16x8*)&lB[t * 16]     = bh;
        *(bf16x8*)&lB[t * 16 + 8] = bl;
    }
    __syncthreads();

    const int lane = t & 63;
    const int half = lane >> 5;    // k-half: 0 -> slots 0-7, 1 -> 8-15
    const int l31  = lane & 31;
    const int wv   = t >> 6;       // 0..15

    const char* __restrict__ aB =
        (const char*)(half ? lAl : lAh) + l31 * 16;

    const int c0 = wv << 1;
    bf16x8 bf0 = *(const bf16x8*)&lB[((((c0)     << 5) + l31) * 2 + half) * 8];
    bf16x8 bf1 = *(const bf16x8*)&lB[((((c0 + 1) << 5) + l31) * 2 + half) * 8];

    f32x16 zf;
#pragma unroll
    for (int j = 0; j < 16; ++j) zf[j] = 0.0f;

    f32x16 acc0, acc1;

    // ---- Prologue: row-tile pair 0 (fold2 peel) ----
    {
        bf16x8 f0 = *(const bf16x8*)(aB);
        bf16x8 f1 = *(const bf16x8*)(aB + 512);
        f32x16 ca = __builtin_amdgcn_mfma_f32_32x32x16_bf16(f0, bf0, zf, 0, 0, 0);
        f32x16 cb = __builtin_amdgcn_mfma_f32_32x32x16_bf16(f1, bf0, zf, 0, 0, 0);
#pragma unroll
        for (int j = 0; j < 16; ++j) acc0[j] = fold2(ca[j], cb[j]);
        f32x16 cc = __builtin_amdgcn_mfma_f32_32x32x16_bf16(f0, bf1, zf, 0, 0, 0);
        f32x16 cd = __builtin_amdgcn_mfma_f32_32x32x16_bf16(f1, bf1, zf, 0, 0, 0);
#pragma unroll
        for (int j = 0; j < 16; ++j) acc1[j] = fold2(cc[j], cd[j]);
    }

    // ---- Rolled main loop (R22; known LDS-BW floor at real clock) ----
#pragma unroll 1
    for (int i = 1; i < 16; ++i) {
        const char* p = aB + (i << 10);
        bf16x8 f0 = *(const bf16x8*)(p);
        bf16x8 f1 = *(const bf16x8*)(p + 512);
        f32x16 ca = __builtin_amdgcn_mfma_f32_32x32x16_bf16(f0, bf0, zf, 0, 0, 0);
        f32x16 cb = __builtin_amdgcn_mfma_f32_32x32x16_bf16(f1, bf0, zf, 0, 0, 0);
#pragma unroll
        for (int j = 0; j < 16; ++j) acc0[j] = fold3(ca[j], cb[j], acc0[j]);
        f32x16 cc = __builtin_amdgcn_mfma_f32_32x32x16_bf16(f0, bf1, zf, 0, 0, 0);
        f32x16 cd = __builtin_amdgcn_mfma_f32_32x32x16_bf16(f1, bf1, zf, 0, 0, 0);
#pragma unroll
        for (int j = 0; j < 16; ++j) acc1[j] = fold3(cc[j], cd[j], acc1[j]);
    }

    // Epilogue: 16->1 tree, cross-half shfl, sqrt, wave-sum.
    float m0 = acc0[0], m1 = acc1[0];
#pragma unroll
    for (int j = 1; j < 16; ++j) { m0 = fminf(m0, acc0[j]); m1 = fminf(m1, acc1[j]); }
    m0 = fminf(m0, __shfl_xor(m0, 32, 64));
    m1 = fminf(m1, __shfl_xor(m1, 32, 64));

    float s = 0.0f;
    if (half == 0)
        s = sqrtf(fmaxf(m0, 0.0f) + 1e-12f) + sqrtf(fmaxf(m1, 0.0f) + 1e-12f);
#pragma unroll
    for (int off = 32; off; off >>= 1) s += __shfl_down(s, off, 64);

    // ---- Block combine + ONE device-scope atomic (no final kernel) ----
    if (lane == 0) wsum[wv] = s;
    __syncthreads();
    if (t == 0) {
        float tot = wsum[0];
#pragma unroll
        for (int k = 1; k < 16; ++k) tot += wsum[k];
        atomicAdd(out, tot);   // out[0] harness-memset to 0 pre-launch
    }
}

extern "C" void kernel_launch(void* const* d_in, const int* in_sizes, int n_in,
                              void* d_out, int out_size, void* d_ws, size_t ws_size,
                              hipStream_t stream) {
    const float4* P = (const float4*)d_in[0];
    const float4* Q = (const float4*)d_in[1];
    float* out  = (float*)d_out;
    (void)d_ws; (void)ws_size;

    chamfer_dir<<<dim3(128 * 2), dim3(1024), 0, stream>>>(P, Q, out);
}